// Round 13
// baseline (161.561 us; speedup 1.0000x reference)
//
#include <hip/hip_runtime.h>
#include <hip/hip_bf16.h>

#define Nn 2
#define Ss 16
#define Cc 64
#define Hh 128
#define Ww 160
#define Gg 8
#define HW (Hh * Ww)        // 20480

// ---------------------------------------------------------------------------
// Transpose [N,C,H,W] -> [N,H,W,C] via LDS tile (src only). grid = 1280.
// ---------------------------------------------------------------------------
__global__ __launch_bounds__(256) void transpose_nchw_nhwc(
    const float* __restrict__ src, float* __restrict__ dst) {
  const int WT = 32;
  __shared__ float tile[Cc][WT + 1];
  int b = blockIdx.x;
  int wt = b % (Ww / WT);
  int h  = (b / (Ww / WT)) % Hh;
  int n  = b / ((Ww / WT) * Hh);
  int w0 = wt * WT;
  int tid = threadIdx.x;
#pragma unroll
  for (int i = 0; i < (Cc * WT) / 256; ++i) {
    int idx = tid + i * 256;
    int c  = idx >> 5;
    int ww = idx & 31;
    tile[c][ww] = src[((n * Cc + c) * Hh + h) * Ww + w0 + ww];
  }
  __syncthreads();
#pragma unroll
  for (int i = 0; i < (Cc * WT) / 256; ++i) {
    int idx = tid + i * 256;
    int ww = idx >> 6;
    int c  = idx & 63;
    dst[((n * Hh + h) * Ww + w0 + ww) * Cc + c] = tile[c][ww];
  }
}

// ---------------------------------------------------------------------------
// Fused main. Wave per (n,hw) point. Lane L = (corner q=L>>4, chan-quad k=L&15).
// Prologue: lane L computes bilinear {w,o} for s=k, corner q (full lane util,
// no redundancy, no prep kernel, no prep-load latency chain).
// Loop: {w,o}(s) fetched via width-16 shfl (2 cy); depth-5 rolling gather
// pipeline; one dwordx4 gather per (point,s) covers 4 corners x 64 channels.
// ---------------------------------------------------------------------------
__global__ __launch_bounds__(256, 8) void corr_fused(
    const float* __restrict__ ref,     // NCHW
    const float* __restrict__ src_t,   // NHWC
    const float* __restrict__ grids, const float* __restrict__ mask,
    float* __restrict__ corr, float* __restrict__ wmask) {
  int nwg = gridDim.x;                     // 5120, divisible by 8
  int q8 = nwg >> 3;
  int bb = blockIdx.x;
  int swz = (bb & 7) * q8 + (bb >> 3);     // bijective XCD chunking
  int wid  = threadIdx.x >> 6;
  int lane = threadIdx.x & 63;
  int k = lane & 15;                       // channel quad (channels 4k..4k+3)
  int q = lane >> 4;                       // corner id
  int hw = swz * 4 + wid;
  int n  = blockIdx.y;

  // ---- prologue: bilinear data for s=k, corner q (reference f32 math) ----
  int nsk = n * Ss + k;
  float xg = grids[(nsk * 2) * HW + hw];
  float yg = grids[(nsk * 2 + 1) * HW + hw];
  float mk = mask[nsk * HW + hw];

  float xn = 2.0f * xg / (float)Ww - 1.0f;
  float yn = 2.0f * yg / (float)Hh - 1.0f;
  float gx = ((xn + 1.0f) * (float)Ww - 1.0f) * 0.5f;
  float gy = ((yn + 1.0f) * (float)Hh - 1.0f) * 0.5f;

  float x0f = floorf(gx), y0f = floorf(gy);
  float dx = gx - x0f, dy = gy - y0f;
  int x0 = (int)x0f, y0 = (int)y0f;
  int x1 = x0 + 1, y1 = y0 + 1;

  float vx0 = (x0 >= 0 && x0 < Ww) ? 1.f : 0.f;
  float vx1 = (x1 >= 0 && x1 < Ww) ? 1.f : 0.f;
  float vy0 = (y0 >= 0 && y0 < Hh) ? 1.f : 0.f;
  float vy1 = (y1 >= 0 && y1 < Hh) ? 1.f : 0.f;

  float w00 = (1.f - dx) * (1.f - dy) * vx0 * vy0;
  float w10 = dx * (1.f - dy) * vx1 * vy0;
  float w01 = (1.f - dx) * dy * vx0 * vy1;
  float w11 = dx * dy * vx1 * vy1;

  float m  = w00 + w10 + w01 + w11;
  float wm = (m < 0.9999f) ? 0.f : 1.f;
  float scale = wm * mk;

  int x0c = min(max(x0, 0), Ww - 1), x1c = min(max(x1, 0), Ww - 1);
  int y0c = min(max(y0, 0), Hh - 1), y1c = min(max(y1, 0), Hh - 1);

  // select this lane's corner, fold scale into the weight
  float wsel = (q & 1) ? ((q & 2) ? w11 : w10) : ((q & 2) ? w01 : w00);
  wsel *= scale;
  int xq = (q & 1) ? x1c : x0c;
  int yq = (q & 2) ? y1c : y0c;
  int osel = yq * Ww + xq;

  if (q == 0) wmask[nsk * HW + hw] = scale;   // lane k writes s=k

  // ref channel quad (NCHW, 4 scalar loads, once per wave)
  const float* refn = ref + (size_t)n * Cc * HW + hw;
  float4 rv;
  rv.x = refn[(4 * k + 0) * HW];
  rv.y = refn[(4 * k + 1) * HW];
  rv.z = refn[(4 * k + 2) * HW];
  rv.w = refn[(4 * k + 3) * HW];

  const float* srcn = src_t + (size_t)n * HW * Cc;
  int cbase = ((n * Gg + (k >> 1)) * Ss) * HW + hw;

  // ---- depth-5 rolling gather pipeline (all indices static via unroll) ----
  const int D = 5;
  float4 v[D]; float wf[D];
#pragma unroll
  for (int i = 0; i < D; ++i) {
    int o  = __shfl(osel, i, 16);
    wf[i]  = __shfl(wsel, i, 16);
    v[i] = *(const float4*)(srcn + ((size_t)o << 6) + (k << 2));
  }
#pragma unroll
  for (int s = 0; s < Ss; ++s) {
    int j = s % D;                       // compile-time under full unroll
    float4 vv = v[j];
    float wcur = wf[j];
    if (s + D < Ss) {                    // issue next gather into this slot
      int o = __shfl(osel, s + D, 16);
      wf[j] = __shfl(wsel, s + D, 16);
      v[j] = *(const float4*)(srcn + ((size_t)o << 6) + (k << 2));
    }
    float d = vv.x * rv.x;
    d = fmaf(vv.y, rv.y, d);
    d = fmaf(vv.z, rv.z, d);
    d = fmaf(vv.w, rv.w, d);
    float p = d * wcur;

    p += __shfl_xor(p, 16);   // sum corner bit0
    p += __shfl_xor(p, 32);   // sum corner bit1
    p += __shfl_xor(p, 1);    // pair quads -> 8-channel group

    if (lane < 16 && (lane & 1) == 0) corr[cbase + s * HW] = p;
  }
}

// ---------------------------------------------------------------------------
// Legacy single-kernel fallback (NCHW, no workspace).
// ---------------------------------------------------------------------------
__global__ __launch_bounds__(256) void corr_kernel_nchw(
    const float* __restrict__ ref, const float* __restrict__ src,
    const float* __restrict__ grids, const float* __restrict__ mask,
    float* __restrict__ corr, float* __restrict__ wmask) {
  int gw   = blockIdx.x * 4 + (threadIdx.x >> 6);
  int lane = threadIdx.x & 63;
  int w  = gw % Ww;
  int hn = gw / Ww;
  int h  = hn % Hh;
  int n  = hn / Hh;

  float rv = ref[((n * Cc + lane) * Hh + h) * Ww + w];

#pragma unroll 4
  for (int s = 0; s < Ss; ++s) {
    int gbase = (((n * Ss + s) * 2) * Hh + h) * Ww + w;
    float xg = grids[gbase];
    float yg = grids[gbase + HW];
    float mk = mask[((n * Ss + s) * Hh + h) * Ww + w];

    float xn = 2.0f * xg / (float)Ww - 1.0f;
    float yn = 2.0f * yg / (float)Hh - 1.0f;
    float gx = ((xn + 1.0f) * (float)Ww - 1.0f) * 0.5f;
    float gy = ((yn + 1.0f) * (float)Hh - 1.0f) * 0.5f;

    float x0f = floorf(gx), y0f = floorf(gy);
    float dx = gx - x0f, dy = gy - y0f;
    int x0 = (int)x0f, y0 = (int)y0f;
    int x1 = x0 + 1, y1 = y0 + 1;

    float vx0 = (x0 >= 0 && x0 < Ww) ? 1.f : 0.f;
    float vx1 = (x1 >= 0 && x1 < Ww) ? 1.f : 0.f;
    float vy0 = (y0 >= 0 && y0 < Hh) ? 1.f : 0.f;
    float vy1 = (y1 >= 0 && y1 < Hh) ? 1.f : 0.f;

    float w00 = (1.f - dx) * (1.f - dy) * vx0 * vy0;
    float w10 = dx * (1.f - dy) * vx1 * vy0;
    float w01 = (1.f - dx) * dy * vx0 * vy1;
    float w11 = dx * dy * vx1 * vy1;

    float m  = w00 + w10 + w01 + w11;
    float wm = (m < 0.9999f) ? 0.f : 1.f;
    float scale = wm * mk;

    float res = 0.f;
    if (scale != 0.f) {
      int x0c = min(max(x0, 0), Ww - 1), x1c = min(max(x1, 0), Ww - 1);
      int y0c = min(max(y0, 0), Hh - 1), y1c = min(max(y1, 0), Hh - 1);
      const float* sp2 = src + (size_t)(n * Cc + lane) * HW;
      float v00 = sp2[y0c * Ww + x0c];
      float v10 = sp2[y0c * Ww + x1c];
      float v01 = sp2[y1c * Ww + x0c];
      float v11 = sp2[y1c * Ww + x1c];
      float acc = w00 * v00 + w10 * v10 + w01 * v01 + w11 * v11;
      float p = acc * rv * scale;
      p += __shfl_xor(p, 1);
      p += __shfl_xor(p, 2);
      p += __shfl_xor(p, 4);
      res = p;
    }
    if ((lane & 7) == 0) {
      int g = lane >> 3;
      corr[((((n * Gg + g) * Ss + s) * Hh + h) * Ww) + w] = res;
    }
    if (lane == 0) wmask[((n * Ss + s) * Hh + h) * Ww + w] = scale;
  }
}

extern "C" void kernel_launch(void* const* d_in, const int* in_sizes, int n_in,
                              void* d_out, int out_size, void* d_ws, size_t ws_size,
                              hipStream_t stream) {
  const float* feat_ref = (const float*)d_in[0];
  const float* feat_src = (const float*)d_in[1];
  const float* grids    = (const float*)d_in[2];
  const float* mask     = (const float*)d_in[3];

  float* corr  = (float*)d_out;
  float* wmask = corr + (size_t)Nn * Gg * Ss * HW;

  const size_t bytes_t = (size_t)Nn * Cc * HW * sizeof(float);  // 10.49 MB

  if (ws_size >= bytes_t) {
    float* src_t = (float*)d_ws;
    transpose_nchw_nhwc<<<Nn * Hh * (Ww / 32), 256, 0, stream>>>(feat_src, src_t);
    corr_fused<<<dim3(HW / 4, Nn), 256, 0, stream>>>(
        feat_ref, src_t, grids, mask, corr, wmask);
  } else {
    corr_kernel_nchw<<<(Nn * HW) / 4, 256, 0, stream>>>(
        feat_ref, feat_src, grids, mask, corr, wmask);
  }
}